// Round 1
// baseline (656.632 us; speedup 1.0000x reference)
//
#include <hip/hip_runtime.h>
#include <hip/hip_bf16.h>
#include <math.h>

#define B_    64
#define T_    256
#define EMB_  300
#define HW_   128
#define G4_   512     // 4*HW
#define HP_   8
#define P1_   46
#define NPOS  (B_*T_) // 16384

__device__ __forceinline__ float rdlane(float v, int l) {
  return __int_as_float(__builtin_amdgcn_readlane(__float_as_int(v), l));
}
__device__ __forceinline__ float sigmoidf_(float x) {
  return 1.0f / (1.0f + __expf(-x));
}

// ---------------------------------------------------------------------------
// Kernel 1: xg = gather(emb, words) @ [WiF;WiB]^T + bias   -> [16384][1024]
// 64x64 output tile per block, K-chunks of 16, fp32.
// ---------------------------------------------------------------------------
__global__ __launch_bounds__(256) void xg_gemm_k(
    const int* __restrict__ words, const float* __restrict__ emb,
    const float* __restrict__ WiF, const float* __restrict__ WiB,
    const float* __restrict__ bF,  const float* __restrict__ bB,
    float* __restrict__ xg) {
  __shared__ float As[16][68];
  __shared__ float Ws[16][68];
  const int m0 = blockIdx.x * 64;
  const int n0 = blockIdx.y * 64;
  const int tid = threadIdx.x;
  const int tx = tid & 15, ty = tid >> 4;
  const int lm = tid >> 2, lk4 = (tid & 3) << 2;

  const int word = words[m0 + lm];
  const float* __restrict__ arow = emb + (long)word * EMB_;
  const int nrow = n0 + lm;
  const float* __restrict__ wrow = (nrow < G4_) ? (WiF + (long)nrow * EMB_)
                                                : (WiB + (long)(nrow - G4_) * EMB_);
  float acc[4][4] = {};
  for (int k0 = 0; k0 < EMB_; k0 += 16) {
    const int k = k0 + lk4;
    float4 av = make_float4(0.f,0.f,0.f,0.f);
    float4 wv = make_float4(0.f,0.f,0.f,0.f);
    if (k < EMB_) {                       // 300 % 4 == 0, so float4 never straddles
      av = *(const float4*)(arow + k);
      wv = *(const float4*)(wrow + k);
    }
    __syncthreads();
    As[lk4+0][lm] = av.x; As[lk4+1][lm] = av.y; As[lk4+2][lm] = av.z; As[lk4+3][lm] = av.w;
    Ws[lk4+0][lm] = wv.x; Ws[lk4+1][lm] = wv.y; Ws[lk4+2][lm] = wv.z; Ws[lk4+3][lm] = wv.w;
    __syncthreads();
    #pragma unroll
    for (int kk = 0; kk < 16; ++kk) {
      const float4 a4 = *(const float4*)&As[kk][ty << 2];
      const float4 w4 = *(const float4*)&Ws[kk][tx << 2];
      const float a[4] = {a4.x, a4.y, a4.z, a4.w};
      const float w[4] = {w4.x, w4.y, w4.z, w4.w};
      #pragma unroll
      for (int i = 0; i < 4; ++i)
        #pragma unroll
        for (int j = 0; j < 4; ++j)
          acc[i][j] += a[i] * w[j];
    }
  }
  const int n = n0 + (tx << 2);
  const float* __restrict__ bb = (n < G4_) ? (bF + n) : (bB + n - G4_);
  #pragma unroll
  for (int i = 0; i < 4; ++i) {
    const int m = m0 + (ty << 2) + i;
    float4 o;
    o.x = acc[i][0] + bb[0];
    o.y = acc[i][1] + bb[1];
    o.z = acc[i][2] + bb[2];
    o.w = acc[i][3] + bb[3];
    *(float4*)&xg[(long)m * 1024 + n] = o;
  }
}

// ---------------------------------------------------------------------------
// Kernel 2: word LSTM recurrence. 128 blocks = (dir, batch); 512 threads.
// Thread r caches Wh row r in VGPRs; h broadcast via readlane.
// ---------------------------------------------------------------------------
__global__ __launch_bounds__(512) void word_lstm_k(
    const float* __restrict__ xg, const float* __restrict__ WhF,
    const float* __restrict__ WhB, float* __restrict__ wo) {
  const int blk = blockIdx.x;
  const int b   = blk & 63;
  const int dir = blk >> 6;
  const int r   = threadIdx.x;          // 0..511 gate row
  const int lane = threadIdx.x & 63;
  const float* __restrict__ Wh = dir ? WhB : WhF;

  float w[128];
  #pragma unroll
  for (int j4 = 0; j4 < 128; j4 += 4) {
    const float4 v = *(const float4*)(Wh + (long)r * 128 + j4);
    w[j4+0] = v.x; w[j4+1] = v.y; w[j4+2] = v.z; w[j4+3] = v.w;
  }

  __shared__ __align__(16) float h_s[128];
  __shared__ float act_s[512];
  float c = 0.f;
  if (r < 128) h_s[r] = 0.f;

  const float* __restrict__ xgp = xg + dir * 512 + r;
  for (int s = 0; s < T_; ++s) {
    __syncthreads();                        // h_s ready (and act_s drained)
    const int tt = dir ? (T_ - 1 - s) : s;
    const long row = (long)(b * T_ + tt);
    float acc = xgp[row * 1024];
    const float2 hp = *(const float2*)&h_s[lane * 2];
    float a0 = 0.f, a1 = 0.f, a2 = 0.f, a3 = 0.f;
    #pragma unroll
    for (int j = 0; j < 64; j += 2) {
      a0 += w[2*j+0] * rdlane(hp.x, j);
      a1 += w[2*j+1] * rdlane(hp.y, j);
      a2 += w[2*j+2] * rdlane(hp.x, j+1);
      a3 += w[2*j+3] * rdlane(hp.y, j+1);
    }
    acc += (a0 + a1) + (a2 + a3);
    // gate order i,f,g,o : rows [0,128) [128,256) [256,384) [384,512)
    const float act = (r >= 256 && r < 384) ? tanhf(acc) : sigmoidf_(acc);
    act_s[r] = act;
    __syncthreads();
    if (r < 128) {
      const float ig = act_s[r];
      const float fg = act_s[128 + r];
      const float gg = act_s[256 + r];
      const float og = act_s[384 + r];
      c = fg * c + ig * gg;
      const float h = og * tanhf(c);
      h_s[r] = h;
      wo[row * 256 + dir * 128 + r] = h;
    }
  }
}

// ---------------------------------------------------------------------------
// Kernel 3: pos LSTM (input is one-hot -> xg = Wi[:,pos]+b). 128 blocks x 64.
// ---------------------------------------------------------------------------
__global__ __launch_bounds__(64) void pos_lstm_k(
    const int* __restrict__ pos,
    const float* __restrict__ WiF, const float* __restrict__ WhF, const float* __restrict__ bF,
    const float* __restrict__ WiB, const float* __restrict__ WhB, const float* __restrict__ bB,
    float* __restrict__ po) {
  const int blk = blockIdx.x;
  const int b   = blk & 63;
  const int dir = blk >> 6;
  const float* __restrict__ Wi = dir ? WiB : WiF;   // [32][46]
  const float* __restrict__ Wh = dir ? WhB : WhF;   // [32][8]
  const float* __restrict__ bias = dir ? bB : bF;

  __shared__ float Wis[32 * P1_];
  const int lane = threadIdx.x;
  for (int i = lane; i < 32 * P1_; i += 64) Wis[i] = Wi[i];
  __syncthreads();

  float w[8] = {};
  float bi = 0.f;
  if (lane < 32) {
    #pragma unroll
    for (int j = 0; j < 8; ++j) w[j] = Wh[lane * 8 + j];
    bi = bias[lane];
  }
  float h[8] = {};
  float cc = 0.f;     // lanes 0..7 hold c
  for (int s = 0; s < T_; ++s) {
    const int tt = dir ? (T_ - 1 - s) : s;
    const int p = pos[b * T_ + tt];
    float acc = 0.f;
    if (lane < 32) {
      acc = Wis[lane * P1_ + p] + bi;
      #pragma unroll
      for (int j = 0; j < 8; ++j) acc += w[j] * h[j];
    }
    // gate order: i(0..7) f(8..15) g(16..23) o(24..31)
    const float act = (lane >= 16 && lane < 24) ? tanhf(acc) : sigmoidf_(acc);
    const float a_f = __shfl_down(act, 8);
    const float a_g = __shfl_down(act, 16);
    const float a_o = __shfl_down(act, 24);
    float hnew = 0.f;
    if (lane < 8) {
      cc = a_f * cc + act * a_g;
      hnew = a_o * tanhf(cc);
      po[(long)(b * T_ + tt) * 16 + dir * 8 + lane] = hnew;
    }
    #pragma unroll
    for (int j = 0; j < 8; ++j) h[j] = __shfl(hnew, j);
  }
}

// ---------------------------------------------------------------------------
// Kernel 4: wh = relu(wo[16384,256] @ whW^T[256,128] + whb)
// ---------------------------------------------------------------------------
__global__ __launch_bounds__(256) void wh_gemm_k(
    const float* __restrict__ A, const float* __restrict__ W,
    const float* __restrict__ bias, float* __restrict__ out) {
  __shared__ float As[16][68];
  __shared__ float Ws[16][68];
  const int m0 = blockIdx.x * 64;
  const int n0 = blockIdx.y * 64;
  const int tid = threadIdx.x;
  const int tx = tid & 15, ty = tid >> 4;
  const int lm = tid >> 2, lk4 = (tid & 3) << 2;
  const float* __restrict__ arow = A + (long)(m0 + lm) * 256;
  const float* __restrict__ wrow = W + (long)(n0 + lm) * 256;
  float acc[4][4] = {};
  for (int k0 = 0; k0 < 256; k0 += 16) {
    const int k = k0 + lk4;
    const float4 av = *(const float4*)(arow + k);
    const float4 wv = *(const float4*)(wrow + k);
    __syncthreads();
    As[lk4+0][lm] = av.x; As[lk4+1][lm] = av.y; As[lk4+2][lm] = av.z; As[lk4+3][lm] = av.w;
    Ws[lk4+0][lm] = wv.x; Ws[lk4+1][lm] = wv.y; Ws[lk4+2][lm] = wv.z; Ws[lk4+3][lm] = wv.w;
    __syncthreads();
    #pragma unroll
    for (int kk = 0; kk < 16; ++kk) {
      const float4 a4 = *(const float4*)&As[kk][ty << 2];
      const float4 w4 = *(const float4*)&Ws[kk][tx << 2];
      const float a[4] = {a4.x, a4.y, a4.z, a4.w};
      const float w[4] = {w4.x, w4.y, w4.z, w4.w};
      #pragma unroll
      for (int i = 0; i < 4; ++i)
        #pragma unroll
        for (int j = 0; j < 4; ++j)
          acc[i][j] += a[i] * w[j];
    }
  }
  const int n = n0 + (tx << 2);
  #pragma unroll
  for (int i = 0; i < 4; ++i) {
    const int m = m0 + (ty << 2) + i;
    float4 o;
    o.x = fmaxf(acc[i][0] + bias[n+0], 0.f);
    o.y = fmaxf(acc[i][1] + bias[n+1], 0.f);
    o.z = fmaxf(acc[i][2] + bias[n+2], 0.f);
    o.w = fmaxf(acc[i][3] + bias[n+3], 0.f);
    *(float4*)&out[(long)m * 128 + n] = o;
  }
}

// ---------------------------------------------------------------------------
// Kernel 5: ph = relu(po@phW^T+phb); feats = relu([wh,ph]@tagW^T + tagb)
// ---------------------------------------------------------------------------
__global__ __launch_bounds__(256) void feats_k(
    const float* __restrict__ wh, const float* __restrict__ po,
    const float* __restrict__ phW, const float* __restrict__ phb,
    const float* __restrict__ tagW, const float* __restrict__ tagb,
    float* __restrict__ feats) {
  __shared__ float phWs[8 * 16], phbs[8], tagWs[6 * 136], tagbs[6];
  const int tid = threadIdx.x;
  for (int i = tid; i < 128; i += 256) phWs[i] = phW[i];
  if (tid < 8) phbs[tid] = phb[tid];
  for (int i = tid; i < 816; i += 256) tagWs[i] = tagW[i];
  if (tid < 6) tagbs[tid] = tagb[tid];
  __syncthreads();
  const int posi = blockIdx.x * 256 + tid;
  const float* __restrict__ por = po + (long)posi * 16;
  float pv[16];
  #pragma unroll
  for (int i = 0; i < 16; i += 4) {
    const float4 v = *(const float4*)(por + i);
    pv[i] = v.x; pv[i+1] = v.y; pv[i+2] = v.z; pv[i+3] = v.w;
  }
  float ph[8];
  #pragma unroll
  for (int o = 0; o < 8; ++o) {
    float a = phbs[o];
    #pragma unroll
    for (int k = 0; k < 16; ++k) a += pv[k] * phWs[o * 16 + k];
    ph[o] = fmaxf(a, 0.f);
  }
  float f[6];
  #pragma unroll
  for (int o = 0; o < 6; ++o) f[o] = tagbs[o];
  const float* __restrict__ whr = wh + (long)posi * 128;
  for (int k = 0; k < 128; k += 4) {
    const float4 v = *(const float4*)(whr + k);
    #pragma unroll
    for (int o = 0; o < 6; ++o)
      f[o] += v.x * tagWs[o*136 + k] + v.y * tagWs[o*136 + k+1]
            + v.z * tagWs[o*136 + k+2] + v.w * tagWs[o*136 + k+3];
  }
  #pragma unroll
  for (int o = 0; o < 6; ++o) {
    #pragma unroll
    for (int k = 0; k < 8; ++k) f[o] += ph[k] * tagWs[o*136 + 128 + k];
    feats[(long)posi * 6 + o] = fmaxf(f[o], 0.f);
  }
}

// ---------------------------------------------------------------------------
// Kernel 6: CRF NLL. One block, 512 threads: 8 lanes per batch element.
// ---------------------------------------------------------------------------
__global__ __launch_bounds__(512) void crf_k(
    const int* __restrict__ words, const int* __restrict__ labels,
    const float* __restrict__ feats, const float* __restrict__ trans,
    float* __restrict__ out) {
  __shared__ float tn_s[36];
  __shared__ float tE_s[6];
  __shared__ float res_s[64];
  const int tid = threadIdx.x;
  if (tid < 36) {
    const int nx = tid / 6, pv = tid % 6;
    float mx = -1e30f;
    for (int q = 0; q < 6; ++q) mx = fmaxf(mx, trans[q * 6 + pv]);
    float s = 0.f;
    for (int q = 0; q < 6; ++q) s += __expf(trans[q * 6 + pv] - mx);
    tn_s[tid] = (pv == 4) ? -100.f : (__expf(trans[nx * 6 + pv] - mx) / s);
  }
  if (tid < 6) tE_s[tid] = trans[4 * 6 + tid];   // raw END row
  __syncthreads();

  const int lane = tid & 63;
  const int wv   = tid >> 6;
  const int sub  = lane & 7;
  const int b    = wv * 8 + (lane >> 3);

  // lengths[b] = count(words[b,:] != 0)
  int cnt = 0;
  for (int t = sub; t < T_; t += 8) cnt += (words[b * T_ + t] != 0) ? 1 : 0;
  cnt += __shfl_xor(cnt, 1); cnt += __shfl_xor(cnt, 2); cnt += __shfl_xor(cnt, 4);
  const int len = cnt;

  float tnr[6];
  #pragma unroll
  for (int p = 0; p < 6; ++p) tnr[p] = (sub < 6) ? tn_s[sub * 6 + p] : -100.f;
  float alpha = (sub == 3) ? 0.f : -100.f;   // START=3
  for (int t = 0; t < T_; ++t) {
    float ap[6];
    #pragma unroll
    for (int p = 0; p < 6; ++p) ap[p] = __shfl(alpha, p, 8) + tnr[p];
    const float feat = (sub < 6) ? feats[(long)(b * T_ + t) * 6 + sub] : 0.f;
    float m = ap[0];
    #pragma unroll
    for (int p = 1; p < 6; ++p) m = fmaxf(m, ap[p]);
    float s = 0.f;
    #pragma unroll
    for (int p = 0; p < 6; ++p) s += __expf(ap[p] - m);
    const float anew = m + __logf(s) + feat;
    alpha = (t < len) ? anew : alpha;
  }
  float v = (sub < 6) ? (alpha + tE_s[sub]) : -1e30f;
  float m2 = v;
  m2 = fmaxf(m2, __shfl_xor(m2, 1));
  m2 = fmaxf(m2, __shfl_xor(m2, 2));
  m2 = fmaxf(m2, __shfl_xor(m2, 4));
  float e = (sub < 6) ? __expf(v - m2) : 0.f;
  e += __shfl_xor(e, 1); e += __shfl_xor(e, 2); e += __shfl_xor(e, 4);
  const float fwd = m2 + __logf(e);

  // gold score
  int fp = T_;
  for (int t = sub; t < T_; t += 8)
    if (labels[b * T_ + t] == 5) fp = min(fp, t);
  fp = min(fp, __shfl_xor(fp, 1));
  fp = min(fp, __shfl_xor(fp, 2));
  fp = min(fp, __shfl_xor(fp, 4));
  float gs = 0.f;
  for (int t = sub; t < T_; t += 8) {
    if (t < fp) {
      const int lab = labels[b * T_ + t];
      const int prv = (t == 0) ? 3 : labels[b * T_ + t - 1];
      gs += feats[(long)(b * T_ + t) * 6 + lab] + tn_s[lab * 6 + prv];
    }
  }
  gs += __shfl_xor(gs, 1); gs += __shfl_xor(gs, 2); gs += __shfl_xor(gs, 4);
  const float gold = gs + trans[4 * 6 + labels[b * T_ + T_ - 1]];
  if (sub == 0) res_s[b] = fwd - gold;
  __syncthreads();
  if (tid == 0) {
    float r = 0.f;
    for (int i = 0; i < 64; ++i) r += res_s[i];
    out[0] = r * (1.0f / 64.0f);
  }
}

// ---------------------------------------------------------------------------
extern "C" void kernel_launch(void* const* d_in, const int* in_sizes, int n_in,
                              void* d_out, int out_size, void* d_ws, size_t ws_size,
                              hipStream_t stream) {
  (void)in_sizes; (void)n_in; (void)out_size; (void)ws_size;
  const int*   words = (const int*)d_in[0];
  const int*   postg = (const int*)d_in[1];
  const int*   labels= (const int*)d_in[2];
  const float* emb_w = (const float*)d_in[3];
  // d_in[4] = emb_p (identity one-hot table) is folded into the pos LSTM gather
  const float* wlfWi = (const float*)d_in[5];
  const float* wlfWh = (const float*)d_in[6];
  const float* wlfb  = (const float*)d_in[7];
  const float* wlbWi = (const float*)d_in[8];
  const float* wlbWh = (const float*)d_in[9];
  const float* wlbb  = (const float*)d_in[10];
  const float* plfWi = (const float*)d_in[11];
  const float* plfWh = (const float*)d_in[12];
  const float* plfb  = (const float*)d_in[13];
  const float* plbWi = (const float*)d_in[14];
  const float* plbWh = (const float*)d_in[15];
  const float* plbb  = (const float*)d_in[16];
  const float* whW   = (const float*)d_in[17];
  const float* whb   = (const float*)d_in[18];
  const float* phW   = (const float*)d_in[19];
  const float* phb   = (const float*)d_in[20];
  const float* tagW  = (const float*)d_in[21];
  const float* tagb  = (const float*)d_in[22];
  const float* trans = (const float*)d_in[23];

  float* ws = (float*)d_ws;
  float* xg = ws;                          // [16384][1024]
  float* wo = xg + (size_t)NPOS * 1024;    // [16384][256]
  float* po = wo + (size_t)NPOS * 256;     // [16384][16]
  float* wh = po + (size_t)NPOS * 16;      // [16384][128]
  float* fe = wh + (size_t)NPOS * 128;     // [16384][6]

  hipLaunchKernelGGL(xg_gemm_k, dim3(NPOS / 64, 1024 / 64), dim3(256), 0, stream,
                     words, emb_w, wlfWi, wlbWi, wlfb, wlbb, xg);
  hipLaunchKernelGGL(word_lstm_k, dim3(128), dim3(512), 0, stream,
                     xg, wlfWh, wlbWh, wo);
  hipLaunchKernelGGL(pos_lstm_k, dim3(128), dim3(64), 0, stream,
                     postg, plfWi, plfWh, plfb, plbWi, plbWh, plbb, po);
  hipLaunchKernelGGL(wh_gemm_k, dim3(NPOS / 64, 128 / 64), dim3(256), 0, stream,
                     wo, whW, whb, wh);
  hipLaunchKernelGGL(feats_k, dim3(NPOS / 256), dim3(256), 0, stream,
                     wh, po, phW, phb, tagW, tagb, fe);
  hipLaunchKernelGGL(crf_k, dim3(1), dim3(512), 0, stream,
                     words, labels, fe, trans, (float*)d_out);
}

// Round 2
// 652.665 us; speedup vs baseline: 1.0061x; 1.0061x over previous
//
#include <hip/hip_runtime.h>
#include <hip/hip_bf16.h>
#include <math.h>

#define B_    64
#define T_    256
#define EMB_  300
#define HW_   128
#define G4_   512     // 4*HW
#define HP_   8
#define P1_   46
#define NPOS  (B_*T_) // 16384

__device__ __forceinline__ float rdlane(float v, int l) {
  return __int_as_float(__builtin_amdgcn_readlane(__float_as_int(v), l));
}
__device__ __forceinline__ float sigmoidf_(float x) {
  return 1.0f / (1.0f + __expf(-x));
}

// ---------------------------------------------------------------------------
// Kernel 1: xg = gather(emb, words) @ [WiF;WiB]^T + bias   -> [16384][1024]
// ---------------------------------------------------------------------------
__global__ __launch_bounds__(256) void xg_gemm_k(
    const int* __restrict__ words, const float* __restrict__ emb,
    const float* __restrict__ WiF, const float* __restrict__ WiB,
    const float* __restrict__ bF,  const float* __restrict__ bB,
    float* __restrict__ xg) {
  __shared__ float As[16][68];
  __shared__ float Ws[16][68];
  const int m0 = blockIdx.x * 64;
  const int n0 = blockIdx.y * 64;
  const int tid = threadIdx.x;
  const int tx = tid & 15, ty = tid >> 4;
  const int lm = tid >> 2, lk4 = (tid & 3) << 2;

  const int word = words[m0 + lm];
  const float* __restrict__ arow = emb + (long)word * EMB_;
  const int nrow = n0 + lm;
  const float* __restrict__ wrow = (nrow < G4_) ? (WiF + (long)nrow * EMB_)
                                                : (WiB + (long)(nrow - G4_) * EMB_);
  float acc[4][4] = {};
  for (int k0 = 0; k0 < EMB_; k0 += 16) {
    const int k = k0 + lk4;
    float4 av = make_float4(0.f,0.f,0.f,0.f);
    float4 wv = make_float4(0.f,0.f,0.f,0.f);
    if (k < EMB_) {                       // 300 % 4 == 0, so float4 never straddles
      av = *(const float4*)(arow + k);
      wv = *(const float4*)(wrow + k);
    }
    __syncthreads();
    As[lk4+0][lm] = av.x; As[lk4+1][lm] = av.y; As[lk4+2][lm] = av.z; As[lk4+3][lm] = av.w;
    Ws[lk4+0][lm] = wv.x; Ws[lk4+1][lm] = wv.y; Ws[lk4+2][lm] = wv.z; Ws[lk4+3][lm] = wv.w;
    __syncthreads();
    #pragma unroll
    for (int kk = 0; kk < 16; ++kk) {
      const float4 a4 = *(const float4*)&As[kk][ty << 2];
      const float4 w4 = *(const float4*)&Ws[kk][tx << 2];
      const float a[4] = {a4.x, a4.y, a4.z, a4.w};
      const float w[4] = {w4.x, w4.y, w4.z, w4.w};
      #pragma unroll
      for (int i = 0; i < 4; ++i)
        #pragma unroll
        for (int j = 0; j < 4; ++j)
          acc[i][j] += a[i] * w[j];
    }
  }
  const int n = n0 + (tx << 2);
  const float* __restrict__ bb = (n < G4_) ? (bF + n) : (bB + n - G4_);
  #pragma unroll
  for (int i = 0; i < 4; ++i) {
    const int m = m0 + (ty << 2) + i;
    float4 o;
    o.x = acc[i][0] + bb[0];
    o.y = acc[i][1] + bb[1];
    o.z = acc[i][2] + bb[2];
    o.w = acc[i][3] + bb[3];
    *(float4*)&xg[(long)m * 1024 + n] = o;
  }
}

// ---------------------------------------------------------------------------
// Kernel 2: word LSTM recurrence. 128 blocks = (dir,batch); 1024 threads.
// Split-K x2: waves 0-7 cover h[0:64], waves 8-15 cover h[64:128].
// Thread map: rr = tid&511 -> q = rr>>2 (h index), g = rr&3 (gate i,f,g,o):
//   4 adjacent lanes hold the 4 gates of one h element -> in-wave shfl exchange.
// ---------------------------------------------------------------------------
__global__ __launch_bounds__(1024) void word_lstm_k(
    const float* __restrict__ xg, const float* __restrict__ WhF,
    const float* __restrict__ WhB, float* __restrict__ wo) {
  const int blk = blockIdx.x;
  const int b   = blk & 63;
  const int dir = blk >> 6;
  const int tid = threadIdx.x;
  const int khalf = tid >> 9;           // 0: k 0..63, 1: k 64..127 (wave-uniform)
  const int rr  = tid & 511;
  const int q   = rr >> 2;              // h index 0..127
  const int g   = rr & 3;               // gate 0=i,1=f,2=g,3=o
  const int lane = tid & 63;
  const float* __restrict__ Wh = dir ? WhB : WhF;

  // weight slice: Wh[g*128+q][khalf*64 + j], j = 0..63
  float w[64];
  {
    const float* __restrict__ wp = Wh + (long)(g * 128 + q) * 128 + khalf * 64;
    #pragma unroll
    for (int j4 = 0; j4 < 64; j4 += 4) {
      const float4 v = *(const float4*)(wp + j4);
      w[j4+0] = v.x; w[j4+1] = v.y; w[j4+2] = v.z; w[j4+3] = v.w;
    }
  }

  __shared__ float psum_s[1024];
  __shared__ float h_s[128];
  if (tid < 128) h_s[tid] = 0.f;
  __syncthreads();
  float hval = h_s[(khalf << 6) + lane];
  float c = 0.f;

  const int col = dir * 512 + g * 128 + q;        // xg column for this thread
  const float* __restrict__ xgc = xg + col;
  float xg_cur = 0.f, xg_next = 0.f;
  {
    const int tt0 = dir ? (T_ - 1) : 0;
    if (khalf == 0) xg_cur = xgc[(long)(b * T_ + tt0) * 1024];
  }

  for (int s = 0; s < T_; ++s) {
    const int tt = dir ? (T_ - 1 - s) : s;
    // prefetch next step's xg (hidden under the FMA loop)
    if (khalf == 0 && s + 1 < T_) {
      const int tn = dir ? (T_ - 2 - s) : (s + 1);
      xg_next = xgc[(long)(b * T_ + tn) * 1024];
    }
    // 64-MAC dot over this thread's K-half
    float a0 = 0.f, a1 = 0.f, a2 = 0.f, a3 = 0.f;
    #pragma unroll
    for (int j = 0; j < 64; j += 4) {
      a0 += w[j+0] * rdlane(hval, j+0);
      a1 += w[j+1] * rdlane(hval, j+1);
      a2 += w[j+2] * rdlane(hval, j+2);
      a3 += w[j+3] * rdlane(hval, j+3);
    }
    psum_s[(khalf << 9) + rr] = (a0 + a1) + (a2 + a3);
    __syncthreads();                       // psum ready; prior h_s reads done
    float h = 0.f;
    if (khalf == 0) {
      const float tot = psum_s[rr] + psum_s[512 + rr] + xg_cur;
      const float act = (g == 2) ? tanhf(tot) : sigmoidf_(tot);
      const int base = lane & ~3;
      const float vi = __shfl(act, base + 0);
      const float vf = __shfl(act, base + 1);
      const float vg = __shfl(act, base + 2);
      const float vo = __shfl(act, base + 3);
      c = vf * c + vi * vg;
      h = vo * tanhf(c);
      if (g == 0) {
        h_s[q] = h;
        wo[(long)(b * T_ + tt) * 256 + dir * 128 + q] = h;
      }
    }
    __syncthreads();                       // h_s ready
    hval = h_s[(khalf << 6) + lane];
    xg_cur = xg_next;
  }
}

// ---------------------------------------------------------------------------
// Kernel 3: pos LSTM (input one-hot -> gather column of Wi). 128 blocks x 64.
// ---------------------------------------------------------------------------
__global__ __launch_bounds__(64) void pos_lstm_k(
    const int* __restrict__ pos,
    const float* __restrict__ WiF, const float* __restrict__ WhF, const float* __restrict__ bF,
    const float* __restrict__ WiB, const float* __restrict__ WhB, const float* __restrict__ bB,
    float* __restrict__ po) {
  const int blk = blockIdx.x;
  const int b   = blk & 63;
  const int dir = blk >> 6;
  const float* __restrict__ Wi = dir ? WiB : WiF;   // [32][46]
  const float* __restrict__ Wh = dir ? WhB : WhF;   // [32][8]
  const float* __restrict__ bias = dir ? bB : bF;

  __shared__ float Wis[32 * P1_];
  const int lane = threadIdx.x;
  for (int i = lane; i < 32 * P1_; i += 64) Wis[i] = Wi[i];
  __syncthreads();

  float w[8] = {};
  float bi = 0.f;
  if (lane < 32) {
    #pragma unroll
    for (int j = 0; j < 8; ++j) w[j] = Wh[lane * 8 + j];
    bi = bias[lane];
  }
  float h[8] = {};
  float cc = 0.f;     // lanes 0..7 hold c
  for (int s = 0; s < T_; ++s) {
    const int tt = dir ? (T_ - 1 - s) : s;
    const int p = pos[b * T_ + tt];
    float acc = 0.f;
    if (lane < 32) {
      acc = Wis[lane * P1_ + p] + bi;
      #pragma unroll
      for (int j = 0; j < 8; ++j) acc += w[j] * h[j];
    }
    const float act = (lane >= 16 && lane < 24) ? tanhf(acc) : sigmoidf_(acc);
    const float a_f = __shfl_down(act, 8);
    const float a_g = __shfl_down(act, 16);
    const float a_o = __shfl_down(act, 24);
    float hnew = 0.f;
    if (lane < 8) {
      cc = a_f * cc + act * a_g;
      hnew = a_o * tanhf(cc);
      po[(long)(b * T_ + tt) * 16 + dir * 8 + lane] = hnew;
    }
    #pragma unroll
    for (int j = 0; j < 8; ++j) h[j] = __shfl(hnew, j);
  }
}

// ---------------------------------------------------------------------------
// Kernel 4: wh = relu(wo[16384,256] @ whW^T[256,128] + whb)
// ---------------------------------------------------------------------------
__global__ __launch_bounds__(256) void wh_gemm_k(
    const float* __restrict__ A, const float* __restrict__ W,
    const float* __restrict__ bias, float* __restrict__ out) {
  __shared__ float As[16][68];
  __shared__ float Ws[16][68];
  const int m0 = blockIdx.x * 64;
  const int n0 = blockIdx.y * 64;
  const int tid = threadIdx.x;
  const int tx = tid & 15, ty = tid >> 4;
  const int lm = tid >> 2, lk4 = (tid & 3) << 2;
  const float* __restrict__ arow = A + (long)(m0 + lm) * 256;
  const float* __restrict__ wrow = W + (long)(n0 + lm) * 256;
  float acc[4][4] = {};
  for (int k0 = 0; k0 < 256; k0 += 16) {
    const int k = k0 + lk4;
    const float4 av = *(const float4*)(arow + k);
    const float4 wv = *(const float4*)(wrow + k);
    __syncthreads();
    As[lk4+0][lm] = av.x; As[lk4+1][lm] = av.y; As[lk4+2][lm] = av.z; As[lk4+3][lm] = av.w;
    Ws[lk4+0][lm] = wv.x; Ws[lk4+1][lm] = wv.y; Ws[lk4+2][lm] = wv.z; Ws[lk4+3][lm] = wv.w;
    __syncthreads();
    #pragma unroll
    for (int kk = 0; kk < 16; ++kk) {
      const float4 a4 = *(const float4*)&As[kk][ty << 2];
      const float4 w4 = *(const float4*)&Ws[kk][tx << 2];
      const float a[4] = {a4.x, a4.y, a4.z, a4.w};
      const float w[4] = {w4.x, w4.y, w4.z, w4.w};
      #pragma unroll
      for (int i = 0; i < 4; ++i)
        #pragma unroll
        for (int j = 0; j < 4; ++j)
          acc[i][j] += a[i] * w[j];
    }
  }
  const int n = n0 + (tx << 2);
  #pragma unroll
  for (int i = 0; i < 4; ++i) {
    const int m = m0 + (ty << 2) + i;
    float4 o;
    o.x = fmaxf(acc[i][0] + bias[n+0], 0.f);
    o.y = fmaxf(acc[i][1] + bias[n+1], 0.f);
    o.z = fmaxf(acc[i][2] + bias[n+2], 0.f);
    o.w = fmaxf(acc[i][3] + bias[n+3], 0.f);
    *(float4*)&out[(long)m * 128 + n] = o;
  }
}

// ---------------------------------------------------------------------------
// Kernel 5: ph = relu(po@phW^T+phb); feats = relu([wh,ph]@tagW^T + tagb)
// ---------------------------------------------------------------------------
__global__ __launch_bounds__(256) void feats_k(
    const float* __restrict__ wh, const float* __restrict__ po,
    const float* __restrict__ phW, const float* __restrict__ phb,
    const float* __restrict__ tagW, const float* __restrict__ tagb,
    float* __restrict__ feats) {
  __shared__ float phWs[8 * 16], phbs[8], tagWs[6 * 136], tagbs[6];
  const int tid = threadIdx.x;
  for (int i = tid; i < 128; i += 256) phWs[i] = phW[i];
  if (tid < 8) phbs[tid] = phb[tid];
  for (int i = tid; i < 816; i += 256) tagWs[i] = tagW[i];
  if (tid < 6) tagbs[tid] = tagb[tid];
  __syncthreads();
  const int posi = blockIdx.x * 256 + tid;
  const float* __restrict__ por = po + (long)posi * 16;
  float pv[16];
  #pragma unroll
  for (int i = 0; i < 16; i += 4) {
    const float4 v = *(const float4*)(por + i);
    pv[i] = v.x; pv[i+1] = v.y; pv[i+2] = v.z; pv[i+3] = v.w;
  }
  float ph[8];
  #pragma unroll
  for (int o = 0; o < 8; ++o) {
    float a = phbs[o];
    #pragma unroll
    for (int k = 0; k < 16; ++k) a += pv[k] * phWs[o * 16 + k];
    ph[o] = fmaxf(a, 0.f);
  }
  float f[6];
  #pragma unroll
  for (int o = 0; o < 6; ++o) f[o] = tagbs[o];
  const float* __restrict__ whr = wh + (long)posi * 128;
  for (int k = 0; k < 128; k += 4) {
    const float4 v = *(const float4*)(whr + k);
    #pragma unroll
    for (int o = 0; o < 6; ++o)
      f[o] += v.x * tagWs[o*136 + k] + v.y * tagWs[o*136 + k+1]
            + v.z * tagWs[o*136 + k+2] + v.w * tagWs[o*136 + k+3];
  }
  #pragma unroll
  for (int o = 0; o < 6; ++o) {
    #pragma unroll
    for (int k = 0; k < 8; ++k) f[o] += ph[k] * tagWs[o*136 + 128 + k];
    feats[(long)posi * 6 + o] = fmaxf(f[o], 0.f);
  }
}

// ---------------------------------------------------------------------------
// Kernel 6: CRF NLL. One block, 512 threads: 8 lanes per batch element.
// ---------------------------------------------------------------------------
__global__ __launch_bounds__(512) void crf_k(
    const int* __restrict__ words, const int* __restrict__ labels,
    const float* __restrict__ feats, const float* __restrict__ trans,
    float* __restrict__ out) {
  __shared__ float tn_s[36];
  __shared__ float tE_s[6];
  __shared__ float res_s[64];
  const int tid = threadIdx.x;
  if (tid < 36) {
    const int nx = tid / 6, pv = tid % 6;
    float mx = -1e30f;
    for (int q = 0; q < 6; ++q) mx = fmaxf(mx, trans[q * 6 + pv]);
    float s = 0.f;
    for (int q = 0; q < 6; ++q) s += __expf(trans[q * 6 + pv] - mx);
    tn_s[tid] = (pv == 4) ? -100.f : (__expf(trans[nx * 6 + pv] - mx) / s);
  }
  if (tid < 6) tE_s[tid] = trans[4 * 6 + tid];   // raw END row
  __syncthreads();

  const int lane = tid & 63;
  const int wv   = tid >> 6;
  const int sub  = lane & 7;
  const int b    = wv * 8 + (lane >> 3);

  int cnt = 0;
  for (int t = sub; t < T_; t += 8) cnt += (words[b * T_ + t] != 0) ? 1 : 0;
  cnt += __shfl_xor(cnt, 1); cnt += __shfl_xor(cnt, 2); cnt += __shfl_xor(cnt, 4);
  const int len = cnt;

  float tnr[6];
  #pragma unroll
  for (int p = 0; p < 6; ++p) tnr[p] = (sub < 6) ? tn_s[sub * 6 + p] : -100.f;
  float alpha = (sub == 3) ? 0.f : -100.f;   // START=3
  for (int t = 0; t < T_; ++t) {
    float ap[6];
    #pragma unroll
    for (int p = 0; p < 6; ++p) ap[p] = __shfl(alpha, p, 8) + tnr[p];
    const float feat = (sub < 6) ? feats[(long)(b * T_ + t) * 6 + sub] : 0.f;
    float m = ap[0];
    #pragma unroll
    for (int p = 1; p < 6; ++p) m = fmaxf(m, ap[p]);
    float s = 0.f;
    #pragma unroll
    for (int p = 0; p < 6; ++p) s += __expf(ap[p] - m);
    const float anew = m + __logf(s) + feat;
    alpha = (t < len) ? anew : alpha;
  }
  float v = (sub < 6) ? (alpha + tE_s[sub]) : -1e30f;
  float m2 = v;
  m2 = fmaxf(m2, __shfl_xor(m2, 1));
  m2 = fmaxf(m2, __shfl_xor(m2, 2));
  m2 = fmaxf(m2, __shfl_xor(m2, 4));
  float e = (sub < 6) ? __expf(v - m2) : 0.f;
  e += __shfl_xor(e, 1); e += __shfl_xor(e, 2); e += __shfl_xor(e, 4);
  const float fwd = m2 + __logf(e);

  int fp = T_;
  for (int t = sub; t < T_; t += 8)
    if (labels[b * T_ + t] == 5) fp = min(fp, t);
  fp = min(fp, __shfl_xor(fp, 1));
  fp = min(fp, __shfl_xor(fp, 2));
  fp = min(fp, __shfl_xor(fp, 4));
  float gs = 0.f;
  for (int t = sub; t < T_; t += 8) {
    if (t < fp) {
      const int lab = labels[b * T_ + t];
      const int prv = (t == 0) ? 3 : labels[b * T_ + t - 1];
      gs += feats[(long)(b * T_ + t) * 6 + lab] + tn_s[lab * 6 + prv];
    }
  }
  gs += __shfl_xor(gs, 1); gs += __shfl_xor(gs, 2); gs += __shfl_xor(gs, 4);
  const float gold = gs + trans[4 * 6 + labels[b * T_ + T_ - 1]];
  if (sub == 0) res_s[b] = fwd - gold;
  __syncthreads();
  if (tid == 0) {
    float r = 0.f;
    for (int i = 0; i < 64; ++i) r += res_s[i];
    out[0] = r * (1.0f / 64.0f);
  }
}

// ---------------------------------------------------------------------------
extern "C" void kernel_launch(void* const* d_in, const int* in_sizes, int n_in,
                              void* d_out, int out_size, void* d_ws, size_t ws_size,
                              hipStream_t stream) {
  (void)in_sizes; (void)n_in; (void)out_size; (void)ws_size;
  const int*   words = (const int*)d_in[0];
  const int*   postg = (const int*)d_in[1];
  const int*   labels= (const int*)d_in[2];
  const float* emb_w = (const float*)d_in[3];
  const float* wlfWi = (const float*)d_in[5];
  const float* wlfWh = (const float*)d_in[6];
  const float* wlfb  = (const float*)d_in[7];
  const float* wlbWi = (const float*)d_in[8];
  const float* wlbWh = (const float*)d_in[9];
  const float* wlbb  = (const float*)d_in[10];
  const float* plfWi = (const float*)d_in[11];
  const float* plfWh = (const float*)d_in[12];
  const float* plfb  = (const float*)d_in[13];
  const float* plbWi = (const float*)d_in[14];
  const float* plbWh = (const float*)d_in[15];
  const float* plbb  = (const float*)d_in[16];
  const float* whW   = (const float*)d_in[17];
  const float* whb   = (const float*)d_in[18];
  const float* phW   = (const float*)d_in[19];
  const float* phb   = (const float*)d_in[20];
  const float* tagW  = (const float*)d_in[21];
  const float* tagb  = (const float*)d_in[22];
  const float* trans = (const float*)d_in[23];

  float* ws = (float*)d_ws;
  float* xg = ws;                          // [16384][1024]
  float* wo = xg + (size_t)NPOS * 1024;    // [16384][256]
  float* po = wo + (size_t)NPOS * 256;     // [16384][16]
  float* wh = po + (size_t)NPOS * 16;      // [16384][128]
  float* fe = wh + (size_t)NPOS * 128;     // [16384][6]

  hipLaunchKernelGGL(xg_gemm_k, dim3(NPOS / 64, 1024 / 64), dim3(256), 0, stream,
                     words, emb_w, wlfWi, wlbWi, wlfb, wlbb, xg);
  hipLaunchKernelGGL(word_lstm_k, dim3(128), dim3(1024), 0, stream,
                     xg, wlfWh, wlbWh, wo);
  hipLaunchKernelGGL(pos_lstm_k, dim3(128), dim3(64), 0, stream,
                     postg, plfWi, plfWh, plfb, plbWi, plbWh, plbb, po);
  hipLaunchKernelGGL(wh_gemm_k, dim3(NPOS / 64, 128 / 64), dim3(256), 0, stream,
                     wo, whW, whb, wh);
  hipLaunchKernelGGL(feats_k, dim3(NPOS / 256), dim3(256), 0, stream,
                     wh, po, phW, phb, tagW, tagb, fe);
  hipLaunchKernelGGL(crf_k, dim3(1), dim3(512), 0, stream,
                     words, labels, fe, trans, (float*)d_out);
}